// Round 10
// baseline (390.847 us; speedup 1.0000x reference)
//
#include <hip/hip_runtime.h>

typedef __bf16 bf16_t;
typedef __bf16 bf16x8 __attribute__((ext_vector_type(8)));
typedef __bf16 bf16x4 __attribute__((ext_vector_type(4)));
typedef unsigned short u16x8 __attribute__((ext_vector_type(8)));
typedef float  f32x4  __attribute__((ext_vector_type(4)));

// ---------------------------------------------------------------------------
// ONE preprocessing launch, independent blocks:
//   [0,4096)     W2 transposes (x then u): 64-row tiles
//   [4096,6144)  W3 transposes (x then u) + scale fold
//   [6144,6272)  prep_w1
//   [6272,6336)  psi0 (from RAW u weights)
//   [6336,6432)  bn_partial
//   [6432,6496)  T-build: per-net lambda-power matrices (re/im) + sigma row sums
__global__ __launch_bounds__(256) void prep_all_kernel(
    const float* __restrict__ xW1, const float* __restrict__ xb1,
    const float* __restrict__ xg,  const float* __restrict__ xbeta,
    const float* __restrict__ uW1, const float* __restrict__ ub1,
    const float* __restrict__ ug,  const float* __restrict__ ubeta,
    const float* __restrict__ xW2, const float* __restrict__ uW2,
    const float* __restrict__ xW3, const float* __restrict__ uW3,
    const float* __restrict__ x_scale, const float* __restrict__ u_scale,
    const float* __restrict__ ub2,
    const float* __restrict__ xs, const float* __restrict__ us,
    const float* __restrict__ reL, const float* __restrict__ imL,
    bf16_t* __restrict__ xW1t, float* __restrict__ xb1p,
    bf16_t* __restrict__ uW1t, float* __restrict__ ub1p,
    bf16_t* __restrict__ xW2t, bf16_t* __restrict__ uW2t,
    bf16_t* __restrict__ xW3t, bf16_t* __restrict__ uW3t,
    float* __restrict__ psi0, float* __restrict__ part,
    bf16_t* __restrict__ As, float* __restrict__ sig_re, float* __restrict__ sig_im)
{
    const int t = blockIdx.x, tid = threadIdx.x;
    __shared__ float tile[32][65];
    __shared__ float h1[256], h2[256];

    if (t < 6144) {
        // ---- weight transposes, 64-row x 32-col tiles ----
        const float* in; bf16_t* outp; const float* scale = nullptr;
        int j, r0, c0, C;
        if (t < 4096) {
            C = 256;
            j = (t & 2047) >> 5;
            const int tl = t & 31; r0 = (tl >> 3) * 64; c0 = (tl & 7) * 32;
            if (t < 2048) { in = xW2; outp = xW2t; }
            else          { in = uW2; outp = uW2t; }
        } else {
            C = 128;
            const int l = t - 4096;
            j = (l & 1023) >> 4;
            const int tl = l & 15; r0 = (tl >> 2) * 64; c0 = (tl & 3) * 32;
            if (l < 1024) { in = xW3; outp = xW3t; scale = x_scale + j * 128; }
            else          { in = uW3; outp = uW3t; scale = u_scale + j * 128; }
        }
        in += (size_t)j * 256 * C;
        bf16_t* op = outp + (size_t)j * 256 * C;
        const int cx = tid & 31, ry0 = tid >> 5;
        #pragma unroll
        for (int p = 0; p < 8; p++)
            tile[cx][ry0 + p * 8] = in[(size_t)(r0 + ry0 + p * 8) * C + c0 + cx];
        __syncthreads();
        const int rr = tid & 63, cb = tid >> 6;
        #pragma unroll
        for (int p = 0; p < 8; p++) {
            const int cl = cb + p * 4;
            float sc = scale ? scale[c0 + cl] : 1.f;
            op[(size_t)(c0 + cl) * 256 + r0 + rr] = (bf16_t)(tile[cl][rr] * sc);
        }
    } else if (t < 6272) {
        // ---- prep_w1 ----
        const int bid = t - 6144, j = bid & 63, h = tid;
        const float *W1, *b1, *gamma, *beta; bf16_t* W1t; float* b1p; int D;
        if (bid < 64) { W1 = xW1; b1 = xb1; gamma = xg; beta = xbeta; W1t = xW1t; b1p = xb1p; D = 16; }
        else          { W1 = uW1; b1 = ub1; gamma = ug; beta = ubeta; W1t = uW1t; b1p = ub1p; D = 8; }
        float bacc = b1[j * 256 + h];
        bf16_t* orow = W1t + (size_t)(j * 256 + h) * 32;
        for (int d = 0; d < 32; d++) orow[d] = (bf16_t)0.f;
        for (int d = 0; d < D; d++) {
            float w = W1[((size_t)j * D + d) * 256 + h];
            orow[d] = (bf16_t)(gamma[j * D + d] * w);
            bacc += beta[j * D + d] * w;
        }
        b1p[j * 256 + h] = bacc;
    } else if (t < 6336) {
        // ---- psi0 from raw u weights ----
        const int j = t - 6272, h = tid;
        {
            float bacc = ub1[j * 256 + h];
            #pragma unroll
            for (int d = 0; d < 8; d++)
                bacc += ubeta[j * 8 + d] * uW1[((size_t)j * 8 + d) * 256 + h];
            h1[h] = fmaxf(bacc, 0.01f * bacc);
        }
        __syncthreads();
        {
            float acc = ub2[j * 256 + h];
            const float* w2 = uW2 + (size_t)j * 65536 + h;
            #pragma unroll 8
            for (int d = 0; d < 256; d++) acc += h1[d] * w2[d * 256];
            h2[h] = fmaxf(acc, 0.01f * acc);
        }
        __syncthreads();
        if (h < 128) {
            float acc = 0.f;
            const float* w3 = uW3 + (size_t)j * 32768 + h;
            #pragma unroll 8
            for (int d = 0; d < 256; d++) acc += h2[d] * w3[d * 128];
            psi0[j * 128 + h] = acc * u_scale[j * 128 + h];
        }
    } else if (t < 6432) {
        // ---- bn_partial ----
        const int bid = t - 6336;
        const bool isx = bid < 64;
        const float* x = isx ? xs : us;
        const int D   = isx ? 16 : 8;
        const int lb  = isx ? bid : bid - 64;
        const int per = isx ? 1024 : 1008;
        const int start = lb * per;
        float a = 0.f, b = 0.f;
        for (int idx = start + tid; idx < start + per; idx += 256) {
            float v = x[idx];
            a += v; b += v * v;
        }
        float* s1 = h1; float* s2 = h2;
        s1[tid] = a; s2[tid] = b;
        __syncthreads();
        if (tid < D) {
            float sa = 0.f, sb = 0.f;
            for (int k = tid; k < 256; k += D) { sa += s1[k]; sb += s2[k]; }
            part[bid * 32 + tid]      = sa;
            part[bid * 32 + 16 + tid] = sb;
        }
    } else {
        // ---- T-build: row r of net j:  T[r][0]=lam^{r+1}, T[r][s]=lam^{r+2-s}
        // (1<=s<=min(r+1,63)), else 0.  sigma[r] = sum_{k=1}^{r+1} lam^k.
        // NOTE: column index clamped <64 (r=63,k=1 would write col 64 -> OOB
        // corrupting Tim[0][0] of the same net — the round-9 bug).
        const int j = t - 6432;
        if (tid < 64) {
            const int r = tid;
            const float lre = reL[j], lim = imL[j];
            bf16_t* Ar = As + ((size_t)(j * 2 + 0) * 64 + r) * 64;
            bf16_t* Ai = As + ((size_t)(j * 2 + 1) * 64 + r) * 64;
            for (int s = 0; s < 64; s++) { Ar[s] = (bf16_t)0.f; Ai[s] = (bf16_t)0.f; }
            float px = 1.f, py = 0.f, sre = 0.f, sim = 0.f;
            for (int k = 1; k <= 64; k++) {
                const float nx = px * lre - py * lim;
                py = px * lim + py * lre;
                px = nx;
                if (k <= r + 1) {
                    sre += px; sim += py;
                    const int col = r + 2 - k;
                    if (col < 64) {
                        Ar[col] = (bf16_t)px;
                        Ai[col] = (bf16_t)py;
                    }
                    if (k == r + 1) { Ar[0] = (bf16_t)px; Ai[0] = (bf16_t)py; }
                }
            }
            sig_re[j * 64 + r] = sre;
            sig_im[j * 64 + r] = sim;
        }
    }
}

// ---------------------------------------------------------------------------
// Fused BN + 3-layer MLP (round-6 known-good shape). Output [j][m][128].
__global__ __launch_bounds__(512, 4) void fused_mlp_kernel(
    const float* __restrict__ xs, const float* __restrict__ us,
    const float* __restrict__ part,
    const bf16_t* __restrict__ xW1t, const float* __restrict__ xb1p,
    const bf16_t* __restrict__ xW2t, const float* __restrict__ xb2,
    const bf16_t* __restrict__ xW3t,
    const bf16_t* __restrict__ uW1t, const float* __restrict__ ub1p,
    const bf16_t* __restrict__ uW2t, const float* __restrict__ ub2,
    const bf16_t* __restrict__ uW3t,
    bf16_t* __restrict__ phi, bf16_t* __restrict__ psiu)
{
    const int bid  = blockIdx.x;
    const int xcd  = bid & 7;
    const int slot = bid >> 3;
    const int band = slot >> 6;
    const int t64  = slot & 63;
    const int j    = xcd * 8 + band;
    const bool is_x = t64 < 32;
    const int tile  = is_x ? t64 : (t64 - 32);

    const float*  In  = is_x ? xs   : us;
    const int     D   = is_x ? 16   : 8;
    const bf16_t* W1t = is_x ? xW1t : uW1t;
    const float*  b1p = is_x ? xb1p : ub1p;
    const bf16_t* W2t = is_x ? xW2t : uW2t;
    const float*  b2  = is_x ? xb2  : ub2;
    const bf16_t* W3t = is_x ? xW3t : uW3t;
    bf16_t* outp      = is_x ? phi  : psiu;
    const int M       = is_x ? 4096 : 4032;

    const int row0 = tile * 128;
    const int tid  = threadIdx.x;
    const int wave = tid >> 6;
    const int lane = tid & 63;
    const int quad = lane >> 4;
    const int l16  = lane & 15;
    const int lo2  = l16 & 3, hi2 = l16 >> 2;

    __shared__ __align__(16) bf16_t hs[128 * 256];
    __shared__ float stats_s[32];

    if (tid < 16) {
        if (is_x) {
            float sa = 0.f, sb = 0.f;
            #pragma unroll 8
            for (int b = 0; b < 64; b++) { sa += part[b * 32 + tid]; sb += part[b * 32 + 16 + tid]; }
            float mu = sa / 4096.f, var = sb / 4096.f - mu * mu;
            stats_s[tid] = mu; stats_s[16 + tid] = rsqrtf(var + 1e-5f);
        } else if (tid < 8) {
            float sa = 0.f, sb = 0.f;
            #pragma unroll 8
            for (int b = 64; b < 96; b++) { sa += part[b * 32 + tid]; sb += part[b * 32 + 16 + tid]; }
            float mu = sa / 4032.f, var = sb / 4032.f - mu * mu;
            stats_s[tid] = mu; stats_s[16 + tid] = rsqrtf(var + 1e-5f);
        }
    }
    __syncthreads();

    const f32x4 vzero = {0.f, 0.f, 0.f, 0.f};

    char* const hsB = (char*)hs;
    const char* const abase = hsB + l16 * 512 + ((quad ^ lo2) << 4);
    const int  wlow0 = (quad >> 1) ^ lo2;
    char* const wbase = hsB + l16 * 512 + ((wave ^ hi2) << 6) + ((quad & 1) << 3);

    // ---------------- layer 1 ----------------
    {
        bf16x8 wfr[2];
        #pragma unroll
        for (int nbi = 0; nbi < 2; nbi++)
            wfr[nbi] = *reinterpret_cast<const bf16x8*>(
                W1t + (size_t)(j * 256 + wave * 32 + nbi * 16 + l16) * 32 + quad * 8);

        f32x4 acc[8][2];
        #pragma unroll
        for (int a = 0; a < 8; a++) { acc[a][0] = vzero; acc[a][1] = vzero; }

        const int c0 = quad * 8;
        #pragma unroll
        for (int mb = 0; mb < 8; mb++) {
            bf16x8 a;
            if (c0 < D) {
                int row = row0 + mb * 16 + l16;
                if (row > M - 1) row = M - 1;
                const float* xp = In + (size_t)row * D + c0;
                f32x4 v0 = *reinterpret_cast<const f32x4*>(xp);
                f32x4 v1 = *reinterpret_cast<const f32x4*>(xp + 4);
                #pragma unroll
                for (int e = 0; e < 4; e++) a[e]     = (bf16_t)((v0[e] - stats_s[c0 + e])     * stats_s[16 + c0 + e]);
                #pragma unroll
                for (int e = 0; e < 4; e++) a[4 + e] = (bf16_t)((v1[e] - stats_s[c0 + 4 + e]) * stats_s[16 + c0 + 4 + e]);
            } else {
                #pragma unroll
                for (int e = 0; e < 8; e++) a[e] = (bf16_t)0.f;
            }
            #pragma unroll
            for (int nbi = 0; nbi < 2; nbi++)
                acc[mb][nbi] = __builtin_amdgcn_mfma_f32_16x16x32_bf16(
                    wfr[nbi], a, acc[mb][nbi], 0, 0, 0);
        }

        #pragma unroll
        for (int nbi = 0; nbi < 2; nbi++) {
            const f32x4 bias = *reinterpret_cast<const f32x4*>(
                b1p + j * 256 + wave * 32 + nbi * 16 + quad * 4);
            char* wp = wbase + ((wlow0 ^ (nbi << 1)) << 4);
            #pragma unroll
            for (int mb = 0; mb < 8; mb++) {
                bf16x4 pk;
                #pragma unroll
                for (int r = 0; r < 4; r++) {
                    float v = acc[mb][nbi][r] + bias[r];
                    v = fmaxf(v, 0.01f * v);
                    pk[r] = (bf16_t)v;
                }
                *reinterpret_cast<bf16x4*>(wp + mb * 8192) = pk;
            }
        }
    }
    __syncthreads();

    // ---------------- layer 2, depth-3 weight ring ----------------
    {
        f32x4 acc[8][2];
        #pragma unroll
        for (int a = 0; a < 8; a++) { acc[a][0] = vzero; acc[a][1] = vzero; }

        const bf16_t* w2base = W2t + ((size_t)j * 256 + wave * 32 + l16) * 256 + quad * 8;

        bf16x8 wr[3][2];
        #pragma unroll
        for (int d = 0; d < 3; d++)
            #pragma unroll
            for (int nbi = 0; nbi < 2; nbi++)
                wr[d][nbi] = *reinterpret_cast<const bf16x8*>(w2base + nbi * 4096 + d * 32);

        #pragma unroll
        for (int kk = 0; kk < 8; kk++) {
            const int c = kk % 3;
            const char* ap = abase + ((kk ^ hi2) << 6);
            bf16x8 av0[4];
            #pragma unroll
            for (int mb = 0; mb < 4; mb++)
                av0[mb] = *reinterpret_cast<const bf16x8*>(ap + mb * 8192);
            #pragma unroll
            for (int nbi = 0; nbi < 2; nbi++)
                #pragma unroll
                for (int mb = 0; mb < 4; mb++)
                    acc[mb][nbi] = __builtin_amdgcn_mfma_f32_16x16x32_bf16(
                        wr[c][nbi], av0[mb], acc[mb][nbi], 0, 0, 0);
            bf16x8 av1[4];
            #pragma unroll
            for (int mb = 0; mb < 4; mb++)
                av1[mb] = *reinterpret_cast<const bf16x8*>(ap + (mb + 4) * 8192);
            #pragma unroll
            for (int nbi = 0; nbi < 2; nbi++)
                #pragma unroll
                for (int mb = 4; mb < 8; mb++)
                    acc[mb][nbi] = __builtin_amdgcn_mfma_f32_16x16x32_bf16(
                        wr[c][nbi], av1[mb - 4], acc[mb][nbi], 0, 0, 0);
            if (kk < 5) {
                #pragma unroll
                for (int nbi = 0; nbi < 2; nbi++)
                    wr[c][nbi] = *reinterpret_cast<const bf16x8*>(
                        w2base + nbi * 4096 + (kk + 3) * 32);
            }
        }
        __syncthreads();
        #pragma unroll
        for (int nbi = 0; nbi < 2; nbi++) {
            const f32x4 bias = *reinterpret_cast<const f32x4*>(
                b2 + j * 256 + wave * 32 + nbi * 16 + quad * 4);
            char* wp = wbase + ((wlow0 ^ (nbi << 1)) << 4);
            #pragma unroll
            for (int mb = 0; mb < 8; mb++) {
                bf16x4 pk;
                #pragma unroll
                for (int r = 0; r < 4; r++) {
                    float v = acc[mb][nbi][r] + bias[r];
                    v = fmaxf(v, 0.01f * v);
                    pk[r] = (bf16_t)v;
                }
                *reinterpret_cast<bf16x4*>(wp + mb * 8192) = pk;
            }
        }
    }
    __syncthreads();

    // ---------------- layer 3, depth-3 weight ring ----------------
    {
        f32x4 acc[8];
        #pragma unroll
        for (int a = 0; a < 8; a++) acc[a] = vzero;

        const bf16_t* w3base = W3t + ((size_t)j * 128 + wave * 16 + l16) * 256 + quad * 8;

        bf16x8 wr[3];
        #pragma unroll
        for (int d = 0; d < 3; d++)
            wr[d] = *reinterpret_cast<const bf16x8*>(w3base + d * 32);

        #pragma unroll
        for (int kk = 0; kk < 8; kk++) {
            const int c = kk % 3;
            const char* ap = abase + ((kk ^ hi2) << 6);
            bf16x8 av0[4];
            #pragma unroll
            for (int mb = 0; mb < 4; mb++)
                av0[mb] = *reinterpret_cast<const bf16x8*>(ap + mb * 8192);
            #pragma unroll
            for (int mb = 0; mb < 4; mb++)
                acc[mb] = __builtin_amdgcn_mfma_f32_16x16x32_bf16(
                    wr[c], av0[mb], acc[mb], 0, 0, 0);
            bf16x8 av1[4];
            #pragma unroll
            for (int mb = 0; mb < 4; mb++)
                av1[mb] = *reinterpret_cast<const bf16x8*>(ap + (mb + 4) * 8192);
            #pragma unroll
            for (int mb = 4; mb < 8; mb++)
                acc[mb] = __builtin_amdgcn_mfma_f32_16x16x32_bf16(
                    wr[c], av1[mb - 4], acc[mb], 0, 0, 0);
            if (kk < 5)
                wr[c] = *reinterpret_cast<const bf16x8*>(w3base + (kk + 3) * 32);
        }
        __syncthreads();
        {
            const int sp3 = (wave * 2 + (quad >> 1)) ^ l16;
            char* w3p = hsB + l16 * 256 + sp3 * 16 + ((quad & 1) << 3);
            #pragma unroll
            for (int mb = 0; mb < 8; mb++) {
                bf16x4 pk;
                #pragma unroll
                for (int r = 0; r < 4; r++) pk[r] = (bf16_t)acc[mb][r];
                *reinterpret_cast<bf16x4*>(w3p + mb * 4096) = pk;
            }
        }
    }
    __syncthreads();
    #pragma unroll
    for (int p = 0; p < 4; p++) {
        const int rr = p * 32 + (tid >> 4);
        const int s  = tid & 15;
        if (row0 + rr < M) {
            bf16x8 v = *reinterpret_cast<const bf16x8*>(hs + rr * 128 + (s ^ (rr & 15)) * 8);
            *reinterpret_cast<bf16x8*>(outp + ((size_t)j * M + row0 + rr) * 128 + s * 8) = v;
        }
    }
}

// ---------------------------------------------------------------------------
// Scan as batched GEMM: block = (b, jc); D[t][c] = sum_{j in chunk} sum_s
// A_j[t][s] * B_{j,b}[s][c], B row s=0 = phi0, s>=1 = raw psiu. Accumulated in
// AGPRs over the 8-net chunk; epilogue mixes re/im via shfl_xor(.,1) and
// stores one fp32 partial per (b,jc).
__global__ __launch_bounds__(256, 2) void scan_gemm_kernel(
    const bf16_t* __restrict__ phi, const bf16_t* __restrict__ psiu,
    const bf16_t* __restrict__ As, float* __restrict__ scr)
{
    const int b  = blockIdx.x >> 3;
    const int jc = blockIdx.x & 7;
    const int tid = threadIdx.x;
    const int wv  = tid >> 6;
    const int lane = tid & 63;
    const int quad = lane >> 4;
    const int l16  = lane & 15;

    __shared__ unsigned Bt[128 * 52];   // [c][s2] packed pairs of s, 26.6 KB

    const f32x4 vzero = {0.f, 0.f, 0.f, 0.f};
    f32x4 accre[8], accim[8];
    #pragma unroll
    for (int i = 0; i < 8; i++) { accre[i] = vzero; accim[i] = vzero; }

    const int s2 = tid >> 3;           // 0..31
    const int c0 = (tid & 7) * 16;

    for (int jj = 0; jj < 8; jj++) {
        const int j = jc * 8 + jj;
        // issue staging loads (overlap with barrier wait)
        const int sA = 2 * s2, sB = 2 * s2 + 1;
        const bf16_t* rowA = (sA == 0)
            ? phi  + ((size_t)j * 4096 + b * 64) * 128
            : psiu + ((size_t)j * 4032 + b * 63 + sA - 1) * 128;
        const bf16_t* rowB = psiu + ((size_t)j * 4032 + b * 63 + sB - 1) * 128;
        u16x8 a0 = *reinterpret_cast<const u16x8*>(rowA + c0);
        u16x8 a1 = *reinterpret_cast<const u16x8*>(rowA + c0 + 8);
        u16x8 b0 = *reinterpret_cast<const u16x8*>(rowB + c0);
        u16x8 b1 = *reinterpret_cast<const u16x8*>(rowB + c0 + 8);
        __syncthreads();   // previous j's LDS reads complete
        #pragma unroll
        for (int e = 0; e < 8; e++)
            Bt[(c0 + e) * 52 + s2] = (unsigned)a0[e] | ((unsigned)b0[e] << 16);
        #pragma unroll
        for (int e = 0; e < 8; e++)
            Bt[(c0 + 8 + e) * 52 + s2] = (unsigned)a1[e] | ((unsigned)b1[e] << 16);
        __syncthreads();
        // 2 K-steps of 32 s
        #pragma unroll
        for (int ks = 0; ks < 2; ks++) {
            bf16x8 Are = *reinterpret_cast<const bf16x8*>(
                As + ((size_t)(j * 2 + 0) * 64 + wv * 16 + l16) * 64 + ks * 32 + quad * 8);
            bf16x8 Aim = *reinterpret_cast<const bf16x8*>(
                As + ((size_t)(j * 2 + 1) * 64 + wv * 16 + l16) * 64 + ks * 32 + quad * 8);
            #pragma unroll
            for (int ct = 0; ct < 8; ct++) {
                bf16x8 Bf = *reinterpret_cast<const bf16x8*>(
                    &Bt[(ct * 16 + l16) * 52 + ks * 16 + quad * 4]);
                accre[ct] = __builtin_amdgcn_mfma_f32_16x16x32_bf16(Are, Bf, accre[ct], 0, 0, 0);
                accim[ct] = __builtin_amdgcn_mfma_f32_16x16x32_bf16(Aim, Bf, accim[ct], 0, 0, 0);
            }
        }
    }

    // epilogue: mix x/y and store partial
    const float sgn = (l16 & 1) ? 1.f : -1.f;
    float* out = scr + ((size_t)(b * 8 + jc) * 64) * 128;
    #pragma unroll
    for (int ct = 0; ct < 8; ct++) {
        const int c = ct * 16 + l16;
        #pragma unroll
        for (int r = 0; r < 4; r++) {
            const float vsw = __shfl_xor(accim[ct][r], 1);
            const int tt = wv * 16 + quad * 4 + r;
            out[tt * 128 + c] = accre[ct][r] + sgn * vsw;
        }
    }
}

// ---------------------------------------------------------------------------
// blocks [0,256): y = (sum_j phi)@C^T (16-row tiles);
// blocks [256,320): decode b: sum partials, subtract sigma*psi0, apply C.
__global__ __launch_bounds__(256) void decode_y_kernel(
    const bf16_t* __restrict__ phi, const float* __restrict__ scr,
    const float* __restrict__ psi0,
    const float* __restrict__ sig_re, const float* __restrict__ sig_im,
    const float* __restrict__ C_W,
    float* __restrict__ y, float* __restrict__ ypred)
{
    const int tid = threadIdx.x;
    __shared__ float Cs[2048];
    __shared__ float S16[16][128];
    __shared__ float sigS[2][64][64];
    __shared__ float psiS[64][128];
    __shared__ float Sd[64][128];

    #pragma unroll
    for (int i = 0; i < 8; i++) Cs[tid + i * 256] = C_W[tid + i * 256];

    if (blockIdx.x < 256) {
        // ---- y ----
        const int m0 = blockIdx.x * 16;
        const int r  = tid >> 4;
        const int cg = (tid & 15) * 8;
        float acc[8];
        #pragma unroll
        for (int e = 0; e < 8; e++) acc[e] = 0.f;
        const bf16_t* p = phi + (size_t)(m0 + r) * 128 + cg;
        for (int j = 0; j < 64; j += 4) {
            bf16x8 v0 = *reinterpret_cast<const bf16x8*>(p + (size_t)j * 524288);
            bf16x8 v1 = *reinterpret_cast<const bf16x8*>(p + (size_t)(j + 1) * 524288);
            bf16x8 v2 = *reinterpret_cast<const bf16x8*>(p + (size_t)(j + 2) * 524288);
            bf16x8 v3 = *reinterpret_cast<const bf16x8*>(p + (size_t)(j + 3) * 524288);
            #pragma unroll
            for (int e = 0; e < 8; e++)
                acc[e] += (float)v0[e] + (float)v1[e] + (float)v2[e] + (float)v3[e];
        }
        #pragma unroll
        for (int e = 0; e < 8; e++) S16[r][cg + e] = acc[e];
        __syncthreads();
        const int mm = tid >> 4, o = tid & 15;
        const int m = m0 + mm;
        if ((m & 63) != 0) {
            float a = 0.f;
            #pragma unroll 8
            for (int l = 0; l < 128; l++) a += S16[mm][l] * Cs[o * 128 + l];
            const int bb = m >> 6, ti = (m & 63) - 1;
            y[(bb * 63 + ti) * 16 + o] = a;
        }
        return;
    }

    // ---- decode for batch b ----
    const int b = blockIdx.x - 256;
    for (int i = tid; i < 4096; i += 256) {
        ((float*)sigS[0])[i] = sig_re[i];
        ((float*)sigS[1])[i] = sig_im[i];
    }
    for (int i = tid; i < 8192; i += 256) ((float*)psiS)[i] = psi0[i];
    __syncthreads();

    const int tt = tid >> 2;           // 0..63
    const int cq = tid & 3;            // 32-col group
    float accv[32];
    {
        const float* base = scr + (size_t)(b * 8) * 8192 + tt * 128 + cq * 32;
        #pragma unroll
        for (int k = 0; k < 8; k++) {
            f32x4 s = *reinterpret_cast<const f32x4*>(base + k * 4);
            #pragma unroll
            for (int p = 1; p < 8; p++) {
                f32x4 v = *reinterpret_cast<const f32x4*>(base + (size_t)p * 8192 + k * 4);
                #pragma unroll
                for (int e = 0; e < 4; e++) s[e] += v[e];
            }
            #pragma unroll
            for (int e = 0; e < 4; e++) accv[k * 4 + e] = s[e];
        }
    }
    // subtract sigma (x) psi0 correction
    for (int j = 0; j < 64; j++) {
        const float sr = sigS[0][j][tt];
        const float si = sigS[1][j][tt];
        #pragma unroll
        for (int k = 0; k < 8; k++) {
            f32x4 pv = *reinterpret_cast<const f32x4*>(&psiS[j][cq * 32 + k * 4]);
            accv[k * 4 + 0] -= sr * pv[0] - si * pv[1];
            accv[k * 4 + 1] -= si * pv[0] + sr * pv[1];
            accv[k * 4 + 2] -= sr * pv[2] - si * pv[3];
            accv[k * 4 + 3] -= si * pv[2] + sr * pv[3];
        }
    }
    #pragma unroll
    for (int k = 0; k < 32; k++) Sd[tt][cq * 32 + k] = accv[k];
    __syncthreads();
    // decode: ypred[b][t][o]
    #pragma unroll
    for (int i = 0; i < 4; i++) {
        const int idx = tid + i * 256;
        if (idx < 1008) {
            const int t = idx >> 4, o = idx & 15;
            float a = 0.f;
            #pragma unroll 8
            for (int l = 0; l < 128; l++) a += Sd[t][l] * Cs[o * 128 + l];
            ypred[(b * 63 + t) * 16 + o] = a;
        }
    }
}

// ---------------------------------------------------------------------------
extern "C" void kernel_launch(void* const* d_in, const int* in_sizes, int n_in,
                              void* d_out, int out_size, void* d_ws, size_t ws_size,
                              hipStream_t stream) {
    const float* xs      = (const float*)d_in[0];
    const float* us      = (const float*)d_in[1];
    const float* x_gamma = (const float*)d_in[2];
    const float* x_beta  = (const float*)d_in[3];
    const float* xW1     = (const float*)d_in[4];
    const float* xb1     = (const float*)d_in[5];
    const float* xW2     = (const float*)d_in[6];
    const float* xb2     = (const float*)d_in[7];
    const float* xW3     = (const float*)d_in[8];
    const float* x_scale = (const float*)d_in[9];
    const float* u_gamma = (const float*)d_in[10];
    const float* u_beta  = (const float*)d_in[11];
    const float* uW1     = (const float*)d_in[12];
    const float* ub1     = (const float*)d_in[13];
    const float* uW2     = (const float*)d_in[14];
    const float* ub2     = (const float*)d_in[15];
    const float* uW3     = (const float*)d_in[16];
    const float* u_scale = (const float*)d_in[17];
    const float* reL     = (const float*)d_in[18];
    const float* imL     = (const float*)d_in[19];
    const float* C_W     = (const float*)d_in[20];

    char* ws = (char*)d_ws;
    size_t off = 0;
    auto alloc = [&](size_t bytes) -> char* {
        char* p = ws + off;
        off += (bytes + 255) & ~(size_t)255;
        return p;
    };
    float*  part = (float*)alloc(96 * 32 * 4);
    bf16_t* xW1t = (bf16_t*)alloc((size_t)64 * 256 * 32 * 2);
    float*  xb1p = (float*) alloc((size_t)64 * 256 * 4);
    bf16_t* xW2t = (bf16_t*)alloc((size_t)64 * 256 * 256 * 2);
    bf16_t* xW3t = (bf16_t*)alloc((size_t)64 * 128 * 256 * 2);
    bf16_t* uW1t = (bf16_t*)alloc((size_t)64 * 256 * 32 * 2);
    float*  ub1p = (float*) alloc((size_t)64 * 256 * 4);
    bf16_t* uW2t = (bf16_t*)alloc((size_t)64 * 256 * 256 * 2);
    bf16_t* uW3t = (bf16_t*)alloc((size_t)64 * 128 * 256 * 2);
    float*  psi0 = (float*) alloc((size_t)64 * 128 * 4);
    bf16_t* As   = (bf16_t*)alloc((size_t)64 * 2 * 64 * 64 * 2);
    float*  sigr = (float*) alloc((size_t)64 * 64 * 4);
    float*  sigi = (float*) alloc((size_t)64 * 64 * 4);
    bf16_t* phi  = (bf16_t*)alloc((size_t)64 * 4096 * 128 * 2);   // [j][m][128]
    bf16_t* psiu = (bf16_t*)alloc((size_t)64 * 4032 * 128 * 2);   // [j][m][128]
    float*  scr  = (float*) alloc((size_t)64 * 8 * 64 * 128 * 4); // gemm partials

    float* y_out     = (float*)d_out;
    float* ypred_out = y_out + 64 * 63 * 16;

    prep_all_kernel<<<6496, 256, 0, stream>>>(
        xW1, xb1, x_gamma, x_beta, uW1, ub1, u_gamma, u_beta,
        xW2, uW2, xW3, uW3, x_scale, u_scale, ub2, xs, us, reL, imL,
        xW1t, xb1p, uW1t, ub1p, xW2t, uW2t, xW3t, uW3t, psi0, part,
        As, sigr, sigi);
    fused_mlp_kernel<<<4096, 512, 0, stream>>>(
        xs, us, part,
        xW1t, xb1p, xW2t, xb2, xW3t, uW1t, ub1p, uW2t, ub2, uW3t, phi, psiu);
    scan_gemm_kernel<<<512, 256, 0, stream>>>(phi, psiu, As, scr);
    decode_y_kernel<<<320, 256, 0, stream>>>(
        phi, scr, psi0, sigr, sigi, C_W, y_out, ypred_out);
}

// Round 11
// 363.838 us; speedup vs baseline: 1.0742x; 1.0742x over previous
//
#include <hip/hip_runtime.h>

typedef __bf16 bf16_t;
typedef __bf16 bf16x8 __attribute__((ext_vector_type(8)));
typedef __bf16 bf16x4 __attribute__((ext_vector_type(4)));
typedef float  f32x4  __attribute__((ext_vector_type(4)));

// ---------------------------------------------------------------------------
// ONE preprocessing launch, independent blocks:
//   [0,4096)      xW2 transpose  (fp32 [j][256][256] -> bf16 [j][256][256]^T)
//   [4096,8192)   uW2 transpose
//   [8192,10240)  xW3 transpose + x_scale fold
//   [10240,12288) uW3 transpose + u_scale fold
//   [12288,12416) prep_w1 (gamma fold, transpose, K-pad; beta fold into b1)
//   [12416,12480) psi0 (from RAW u weights; computes ub1p inline)
//   [12480,12576) bn_partial (per-feature sum/sumsq partials)
__global__ __launch_bounds__(256) void prep_all_kernel(
    const float* __restrict__ xW1, const float* __restrict__ xb1,
    const float* __restrict__ xg,  const float* __restrict__ xbeta,
    const float* __restrict__ uW1, const float* __restrict__ ub1,
    const float* __restrict__ ug,  const float* __restrict__ ubeta,
    const float* __restrict__ xW2, const float* __restrict__ uW2,
    const float* __restrict__ xW3, const float* __restrict__ uW3,
    const float* __restrict__ x_scale, const float* __restrict__ u_scale,
    const float* __restrict__ ub2,
    const float* __restrict__ xs, const float* __restrict__ us,
    bf16_t* __restrict__ xW1t, float* __restrict__ xb1p,
    bf16_t* __restrict__ uW1t, float* __restrict__ ub1p,
    bf16_t* __restrict__ xW2t, bf16_t* __restrict__ uW2t,
    bf16_t* __restrict__ xW3t, bf16_t* __restrict__ uW3t,
    float* __restrict__ psi0, float* __restrict__ part)
{
    const int t = blockIdx.x, tid = threadIdx.x;
    __shared__ float tile[32][33];
    __shared__ float h1[256], h2[256];

    if (t < 12288) {
        // ---- weight transposes ----
        const float* in; bf16_t* outp; const float* scale = nullptr;
        int j, r0, c0, C;
        if (t < 8192) {
            C = 256;
            j = (t & 4095) >> 6;
            const int tl = t & 63; r0 = (tl >> 3) * 32; c0 = (tl & 7) * 32;
            if (t < 4096) { in = xW2; outp = xW2t; }
            else          { in = uW2; outp = uW2t; }
        } else {
            C = 128;
            const int l = t - 8192;
            j = (l & 2047) >> 5;
            const int tl = l & 31; r0 = (tl >> 2) * 32; c0 = (tl & 3) * 32;
            if (l < 2048) { in = xW3; outp = xW3t; scale = x_scale + j * 128; }
            else          { in = uW3; outp = uW3t; scale = u_scale + j * 128; }
        }
        const int R = 256;
        in   += (size_t)j * R * C;
        bf16_t* op = outp + (size_t)j * R * C;
        const int tx = tid & 31, ty = tid >> 5;
        #pragma unroll
        for (int i = 0; i < 4; i++)
            tile[ty + i * 8][tx] = in[(size_t)(r0 + ty + i * 8) * C + c0 + tx];
        __syncthreads();
        #pragma unroll
        for (int i = 0; i < 4; i++) {
            int c = c0 + ty + i * 8;
            float sc = scale ? scale[c] : 1.f;
            op[(size_t)c * R + r0 + tx] = (bf16_t)(tile[tx][ty + i * 8] * sc);
        }
    } else if (t < 12416) {
        // ---- prep_w1 ----
        const int bid = t - 12288, j = bid & 63, h = tid;
        const float *W1, *b1, *gamma, *beta; bf16_t* W1t; float* b1p; int D;
        if (bid < 64) { W1 = xW1; b1 = xb1; gamma = xg; beta = xbeta; W1t = xW1t; b1p = xb1p; D = 16; }
        else          { W1 = uW1; b1 = ub1; gamma = ug; beta = ubeta; W1t = uW1t; b1p = ub1p; D = 8; }
        float bacc = b1[j * 256 + h];
        bf16_t* orow = W1t + (size_t)(j * 256 + h) * 32;
        for (int d = 0; d < 32; d++) orow[d] = (bf16_t)0.f;
        for (int d = 0; d < D; d++) {
            float w = W1[((size_t)j * D + d) * 256 + h];
            orow[d] = (bf16_t)(gamma[j * D + d] * w);
            bacc += beta[j * D + d] * w;
        }
        b1p[j * 256 + h] = bacc;
    } else if (t < 12480) {
        // ---- psi0 from raw u weights (no deps on other blocks) ----
        const int j = t - 12416, h = tid;
        {
            float bacc = ub1[j * 256 + h];
            #pragma unroll
            for (int d = 0; d < 8; d++)
                bacc += ubeta[j * 8 + d] * uW1[((size_t)j * 8 + d) * 256 + h];
            h1[h] = fmaxf(bacc, 0.01f * bacc);
        }
        __syncthreads();
        {
            float acc = ub2[j * 256 + h];
            const float* w2 = uW2 + (size_t)j * 65536 + h;
            #pragma unroll 8
            for (int d = 0; d < 256; d++) acc += h1[d] * w2[d * 256];
            h2[h] = fmaxf(acc, 0.01f * acc);
        }
        __syncthreads();
        if (h < 128) {
            float acc = 0.f;
            const float* w3 = uW3 + (size_t)j * 32768 + h;
            #pragma unroll 8
            for (int d = 0; d < 256; d++) acc += h2[d] * w3[d * 128];
            psi0[j * 128 + h] = acc * u_scale[j * 128 + h];
        }
    } else {
        // ---- bn_partial ----
        const int bid = t - 12480;
        const bool isx = bid < 64;
        const float* x = isx ? xs : us;
        const int D   = isx ? 16 : 8;
        const int lb  = isx ? bid : bid - 64;
        const int per = isx ? 1024 : 1008;
        const int start = lb * per;
        float a = 0.f, b = 0.f;
        for (int idx = start + tid; idx < start + per; idx += 256) {
            float v = x[idx];
            a += v; b += v * v;
        }
        float* s1 = h1; float* s2 = h2;
        s1[tid] = a; s2[tid] = b;
        __syncthreads();
        if (tid < D) {
            float sa = 0.f, sb = 0.f;
            for (int k = tid; k < 256; k += D) { sa += s1[k]; sb += s2[k]; }
            part[bid * 32 + tid]      = sa;
            part[bid * 32 + 16 + tid] = sb;
        }
    }
}

// ---------------------------------------------------------------------------
// Fused BN + 3-layer MLP. 512 threads, m-tile 128, A=weights B=activations.
// BN-final inlined (reads `part`). Swizzle decomposed into per-thread
// constants + one xor per kk; mb strides are immediate offsets.
// Output [j][m][128]. XCD j-banding: xcd = bid&7 owns nets xcd*8..+7.
__global__ __launch_bounds__(512, 4) void fused_mlp_kernel(
    const float* __restrict__ xs, const float* __restrict__ us,
    const float* __restrict__ part,
    const bf16_t* __restrict__ xW1t, const float* __restrict__ xb1p,
    const bf16_t* __restrict__ xW2t, const float* __restrict__ xb2,
    const bf16_t* __restrict__ xW3t,
    const bf16_t* __restrict__ uW1t, const float* __restrict__ ub1p,
    const bf16_t* __restrict__ uW2t, const float* __restrict__ ub2,
    const bf16_t* __restrict__ uW3t,
    bf16_t* __restrict__ phi, bf16_t* __restrict__ psiu)
{
    const int bid  = blockIdx.x;
    const int xcd  = bid & 7;
    const int slot = bid >> 3;          // 0..511
    const int band = slot >> 6;         // 0..7
    const int t64  = slot & 63;
    const int j    = xcd * 8 + band;
    const bool is_x = t64 < 32;
    const int tile  = is_x ? t64 : (t64 - 32);

    const float*  In  = is_x ? xs   : us;
    const int     D   = is_x ? 16   : 8;
    const bf16_t* W1t = is_x ? xW1t : uW1t;
    const float*  b1p = is_x ? xb1p : ub1p;
    const bf16_t* W2t = is_x ? xW2t : uW2t;
    const float*  b2  = is_x ? xb2  : ub2;
    const bf16_t* W3t = is_x ? xW3t : uW3t;
    bf16_t* outp      = is_x ? phi  : psiu;
    const int M       = is_x ? 4096 : 4032;

    const int row0 = tile * 128;
    const int tid  = threadIdx.x;
    const int wave = tid >> 6;          // 0..7
    const int lane = tid & 63;
    const int quad = lane >> 4;
    const int l16  = lane & 15;
    const int lo2  = l16 & 3, hi2 = l16 >> 2;

    __shared__ __align__(16) bf16_t hs[128 * 256];   // 64 KB, reused
    __shared__ float stats_s[32];                    // [mu(16), rstd(16)]

    // ---- inline BN final ----
    if (tid < 16) {
        if (is_x) {
            float sa = 0.f, sb = 0.f;
            #pragma unroll 8
            for (int b = 0; b < 64; b++) { sa += part[b * 32 + tid]; sb += part[b * 32 + 16 + tid]; }
            float mu = sa / 4096.f, var = sb / 4096.f - mu * mu;
            stats_s[tid] = mu; stats_s[16 + tid] = rsqrtf(var + 1e-5f);
        } else if (tid < 8) {
            float sa = 0.f, sb = 0.f;
            #pragma unroll 8
            for (int b = 64; b < 96; b++) { sa += part[b * 32 + tid]; sb += part[b * 32 + 16 + tid]; }
            float mu = sa / 4032.f, var = sb / 4032.f - mu * mu;
            stats_s[tid] = mu; stats_s[16 + tid] = rsqrtf(var + 1e-5f);
        }
    }
    __syncthreads();

    const f32x4 vzero = {0.f, 0.f, 0.f, 0.f};

    // per-thread swizzle constants (bytes)
    char* const hsB = (char*)hs;
    const char* const abase = hsB + l16 * 512 + ((quad ^ lo2) << 4);   // A-frag reads
    const int  wlow0 = (quad >> 1) ^ lo2;
    char* const wbase = hsB + l16 * 512 + ((wave ^ hi2) << 6) + ((quad & 1) << 3);

    // ---------------- layer 1 (K=32, BN folded in) ----------------
    {
        bf16x8 wfr[2];
        #pragma unroll
        for (int nbi = 0; nbi < 2; nbi++)
            wfr[nbi] = *reinterpret_cast<const bf16x8*>(
                W1t + (size_t)(j * 256 + wave * 32 + nbi * 16 + l16) * 32 + quad * 8);

        f32x4 acc[8][2];
        #pragma unroll
        for (int a = 0; a < 8; a++) { acc[a][0] = vzero; acc[a][1] = vzero; }

        const int c0 = quad * 8;
        #pragma unroll
        for (int mb = 0; mb < 8; mb++) {
            bf16x8 a;
            if (c0 < D) {
                int row = row0 + mb * 16 + l16;
                if (row > M - 1) row = M - 1;
                const float* xp = In + (size_t)row * D + c0;
                f32x4 v0 = *reinterpret_cast<const f32x4*>(xp);
                f32x4 v1 = *reinterpret_cast<const f32x4*>(xp + 4);
                #pragma unroll
                for (int e = 0; e < 4; e++) a[e]     = (bf16_t)((v0[e] - stats_s[c0 + e])     * stats_s[16 + c0 + e]);
                #pragma unroll
                for (int e = 0; e < 4; e++) a[4 + e] = (bf16_t)((v1[e] - stats_s[c0 + 4 + e]) * stats_s[16 + c0 + 4 + e]);
            } else {
                #pragma unroll
                for (int e = 0; e < 8; e++) a[e] = (bf16_t)0.f;
            }
            #pragma unroll
            for (int nbi = 0; nbi < 2; nbi++)
                acc[mb][nbi] = __builtin_amdgcn_mfma_f32_16x16x32_bf16(
                    wfr[nbi], a, acc[mb][nbi], 0, 0, 0);
        }

        #pragma unroll
        for (int nbi = 0; nbi < 2; nbi++) {
            const f32x4 bias = *reinterpret_cast<const f32x4*>(
                b1p + j * 256 + wave * 32 + nbi * 16 + quad * 4);
            char* wp = wbase + ((wlow0 ^ (nbi << 1)) << 4);
            #pragma unroll
            for (int mb = 0; mb < 8; mb++) {
                bf16x4 pk;
                #pragma unroll
                for (int r = 0; r < 4; r++) {
                    float v = acc[mb][nbi][r] + bias[r];
                    v = fmaxf(v, 0.01f * v);
                    pk[r] = (bf16_t)v;
                }
                *reinterpret_cast<bf16x4*>(wp + mb * 8192) = pk;
            }
        }
    }
    __syncthreads();

    // ---------------- layer 2 (256x256), depth-3 weight ring ----------------
    {
        f32x4 acc[8][2];
        #pragma unroll
        for (int a = 0; a < 8; a++) { acc[a][0] = vzero; acc[a][1] = vzero; }

        const bf16_t* w2base = W2t + ((size_t)j * 256 + wave * 32 + l16) * 256 + quad * 8;

        bf16x8 wr[3][2];
        #pragma unroll
        for (int d = 0; d < 3; d++)
            #pragma unroll
            for (int nbi = 0; nbi < 2; nbi++)
                wr[d][nbi] = *reinterpret_cast<const bf16x8*>(w2base + nbi * 4096 + d * 32);

        #pragma unroll
        for (int kk = 0; kk < 8; kk++) {
            const int c = kk % 3;
            const char* ap = abase + ((kk ^ hi2) << 6);
            bf16x8 av0[4];
            #pragma unroll
            for (int mb = 0; mb < 4; mb++)
                av0[mb] = *reinterpret_cast<const bf16x8*>(ap + mb * 8192);
            #pragma unroll
            for (int nbi = 0; nbi < 2; nbi++)
                #pragma unroll
                for (int mb = 0; mb < 4; mb++)
                    acc[mb][nbi] = __builtin_amdgcn_mfma_f32_16x16x32_bf16(
                        wr[c][nbi], av0[mb], acc[mb][nbi], 0, 0, 0);
            bf16x8 av1[4];
            #pragma unroll
            for (int mb = 0; mb < 4; mb++)
                av1[mb] = *reinterpret_cast<const bf16x8*>(ap + (mb + 4) * 8192);
            #pragma unroll
            for (int nbi = 0; nbi < 2; nbi++)
                #pragma unroll
                for (int mb = 4; mb < 8; mb++)
                    acc[mb][nbi] = __builtin_amdgcn_mfma_f32_16x16x32_bf16(
                        wr[c][nbi], av1[mb - 4], acc[mb][nbi], 0, 0, 0);
            if (kk < 5) {
                #pragma unroll
                for (int nbi = 0; nbi < 2; nbi++)
                    wr[c][nbi] = *reinterpret_cast<const bf16x8*>(
                        w2base + nbi * 4096 + (kk + 3) * 32);
            }
        }
        __syncthreads();
        #pragma unroll
        for (int nbi = 0; nbi < 2; nbi++) {
            const f32x4 bias = *reinterpret_cast<const f32x4*>(
                b2 + j * 256 + wave * 32 + nbi * 16 + quad * 4);
            char* wp = wbase + ((wlow0 ^ (nbi << 1)) << 4);
            #pragma unroll
            for (int mb = 0; mb < 8; mb++) {
                bf16x4 pk;
                #pragma unroll
                for (int r = 0; r < 4; r++) {
                    float v = acc[mb][nbi][r] + bias[r];
                    v = fmaxf(v, 0.01f * v);
                    pk[r] = (bf16_t)v;
                }
                *reinterpret_cast<bf16x4*>(wp + mb * 8192) = pk;
            }
        }
    }
    __syncthreads();

    // ---------------- layer 3 (256x128), depth-3 weight ring ----------------
    {
        f32x4 acc[8];
        #pragma unroll
        for (int a = 0; a < 8; a++) acc[a] = vzero;

        const bf16_t* w3base = W3t + ((size_t)j * 128 + wave * 16 + l16) * 256 + quad * 8;

        bf16x8 wr[3];
        #pragma unroll
        for (int d = 0; d < 3; d++)
            wr[d] = *reinterpret_cast<const bf16x8*>(w3base + d * 32);

        #pragma unroll
        for (int kk = 0; kk < 8; kk++) {
            const int c = kk % 3;
            const char* ap = abase + ((kk ^ hi2) << 6);
            bf16x8 av0[4];
            #pragma unroll
            for (int mb = 0; mb < 4; mb++)
                av0[mb] = *reinterpret_cast<const bf16x8*>(ap + mb * 8192);
            #pragma unroll
            for (int mb = 0; mb < 4; mb++)
                acc[mb] = __builtin_amdgcn_mfma_f32_16x16x32_bf16(
                    wr[c], av0[mb], acc[mb], 0, 0, 0);
            bf16x8 av1[4];
            #pragma unroll
            for (int mb = 0; mb < 4; mb++)
                av1[mb] = *reinterpret_cast<const bf16x8*>(ap + (mb + 4) * 8192);
            #pragma unroll
            for (int mb = 4; mb < 8; mb++)
                acc[mb] = __builtin_amdgcn_mfma_f32_16x16x32_bf16(
                    wr[c], av1[mb - 4], acc[mb], 0, 0, 0);
            if (kk < 5)
                wr[c] = *reinterpret_cast<const bf16x8*>(w3base + (kk + 3) * 32);
        }
        __syncthreads();   // hs reusable as [128][128]
        {
            const int sp3 = (wave * 2 + (quad >> 1)) ^ l16;
            char* w3p = hsB + l16 * 256 + sp3 * 16 + ((quad & 1) << 3);
            #pragma unroll
            for (int mb = 0; mb < 8; mb++) {
                bf16x4 pk;
                #pragma unroll
                for (int r = 0; r < 4; r++) pk[r] = (bf16_t)acc[mb][r];
                *reinterpret_cast<bf16x4*>(w3p + mb * 4096) = pk;
            }
        }
    }
    __syncthreads();
    #pragma unroll
    for (int p = 0; p < 4; p++) {
        const int rr = p * 32 + (tid >> 4);
        const int s  = tid & 15;
        if (row0 + rr < M) {
            bf16x8 v = *reinterpret_cast<const bf16x8*>(hs + rr * 128 + (s ^ (rr & 15)) * 8);
            *reinterpret_cast<bf16x8*>(outp + ((size_t)j * M + row0 + rr) * 128 + s * 8) = v;
        }
    }
}

// ---------------------------------------------------------------------------
// y = (sum_j phi[j][m][:]) @ C^T. 256 blocks x 16-row tiles.
__global__ __launch_bounds__(256) void y_kernel(
    const bf16_t* __restrict__ phi, const float* __restrict__ C_W,
    float* __restrict__ y) {
    const int m0 = blockIdx.x * 16;
    const int tid = threadIdx.x;
    __shared__ float S[16][128];
    __shared__ float Cs[2048];
    #pragma unroll
    for (int i = 0; i < 8; i++) Cs[tid + i * 256] = C_W[tid + i * 256];
    const int r  = tid >> 4;            // 0..15
    const int cg = (tid & 15) * 8;      // 8-col group
    float acc[8];
    #pragma unroll
    for (int e = 0; e < 8; e++) acc[e] = 0.f;
    const bf16_t* p = phi + (size_t)(m0 + r) * 128 + cg;
    for (int j = 0; j < 64; j++) {
        bf16x8 v = *reinterpret_cast<const bf16x8*>(p + (size_t)j * 524288);
        #pragma unroll
        for (int e = 0; e < 8; e++) acc[e] += (float)v[e];
    }
    #pragma unroll
    for (int e = 0; e < 8; e++) S[r][cg + e] = acc[e];
    __syncthreads();
    const int mm = tid >> 4, o = tid & 15;
    const int m = m0 + mm;
    if ((m & 63) != 0) {
        float a = 0.f;
        #pragma unroll 8
        for (int l = 0; l < 128; l++) a += S[mm][l] * Cs[o * 128 + l];
        const int b = m >> 6, ti = (m & 63) - 1;
        y[(b * 63 + ti) * 16 + o] = a;
    }
}

// Koopman scan, split over j: block = (b, jg) handles 8 nets, 4 waves x 2 nets.
// Prefetches t+1's psiu before t's reduce to hide load latency.
__global__ __launch_bounds__(256) void scan_kernel(
    const bf16_t* __restrict__ phi, const bf16_t* __restrict__ psiu,
    const float* __restrict__ psi0, const float* __restrict__ reL,
    const float* __restrict__ imL, float* __restrict__ scratch) {
    const int b = blockIdx.x >> 3, jg = blockIdx.x & 7;
    const int tid = threadIdx.x;
    const int wave = tid >> 6, lane = tid & 63;
    __shared__ float red[2][4][128];

    const int j0 = jg * 8 + wave * 2;
    float sx0, sy0, sx1, sy1;
    float p0x0, p0y0, p0x1, p0y1, lre0, lim0, lre1, lim1;
    {
        unsigned v0 = *reinterpret_cast<const unsigned*>(
            phi + ((size_t)j0 * 4096 + b * 64) * 128 + lane * 2);
        unsigned v1 = *reinterpret_cast<const unsigned*>(
            phi + ((size_t)(j0 + 1) * 4096 + b * 64) * 128 + lane * 2);
        sx0 = __uint_as_float(v0 << 16); sy0 = __uint_as_float(v0 & 0xFFFF0000u);
        sx1 = __uint_as_float(v1 << 16); sy1 = __uint_as_float(v1 & 0xFFFF0000u);
        float2 p0 = *reinterpret_cast<const float2*>(psi0 + j0 * 128 + lane * 2);
        float2 p1 = *reinterpret_cast<const float2*>(psi0 + (j0 + 1) * 128 + lane * 2);
        p0x0 = p0.x; p0y0 = p0.y; p0x1 = p1.x; p0y1 = p1.y;
        lre0 = reL[j0]; lim0 = imL[j0]; lre1 = reL[j0 + 1]; lim1 = imL[j0 + 1];
    }
    const bf16_t* up0 = psiu + ((size_t)j0 * 4032 + b * 63) * 128 + lane * 2;
    const bf16_t* up1 = psiu + ((size_t)(j0 + 1) * 4032 + b * 63) * 128 + lane * 2;
    unsigned cur0 = *reinterpret_cast<const unsigned*>(up0);
    unsigned cur1 = *reinterpret_cast<const unsigned*>(up1);
    float* out = scratch + (size_t)blockIdx.x * 63 * 128;

    for (int t = 0; t < 63; t++) {
        unsigned nx0 = 0, nx1 = 0;
        if (t < 62) {
            nx0 = *reinterpret_cast<const unsigned*>(up0 + (t + 1) * 128);
            nx1 = *reinterpret_cast<const unsigned*>(up1 + (t + 1) * 128);
        }
        float px = sx0 + (__uint_as_float(cur0 << 16) - p0x0);
        float py = sy0 + (__uint_as_float(cur0 & 0xFFFF0000u) - p0y0);
        sx0 = px * lre0 - py * lim0;
        sy0 = px * lim0 + py * lre0;
        px = sx1 + (__uint_as_float(cur1 << 16) - p0x1);
        py = sy1 + (__uint_as_float(cur1 & 0xFFFF0000u) - p0y1);
        sx1 = px * lre1 - py * lim1;
        sy1 = px * lim1 + py * lre1;
        const int db = t & 1;
        red[db][wave][lane * 2]     = sx0 + sx1;
        red[db][wave][lane * 2 + 1] = sy0 + sy1;
        __syncthreads();
        if (tid < 128)
            out[t * 128 + tid] = red[db][0][tid] + red[db][1][tid]
                               + red[db][2][tid] + red[db][3][tid];
        cur0 = nx0; cur1 = nx1;
    }
}

// Sum the 8 j-group partials and decode: ypred[b][t][16]. One wave per (t,b).
__global__ __launch_bounds__(64) void decode_kernel(
    const float* __restrict__ scratch, const float* __restrict__ C_W,
    float* __restrict__ ypred) {
    const int t = blockIdx.x, b = blockIdx.y, l = threadIdx.x;
    __shared__ float S[128];
    float s0 = 0.f, s1 = 0.f;
    #pragma unroll
    for (int jg = 0; jg < 8; jg++) {
        float2 v = *reinterpret_cast<const float2*>(
            scratch + ((size_t)(b * 8 + jg) * 63 + t) * 128 + l * 2);
        s0 += v.x; s1 += v.y;
    }
    S[l * 2] = s0; S[l * 2 + 1] = s1;
    __syncthreads();
    const int o = l >> 2, q = l & 3;
    float acc = 0.f;
    #pragma unroll
    for (int i = 0; i < 32; i++)
        acc += S[q * 32 + i] * C_W[o * 128 + q * 32 + i];
    acc += __shfl_xor(acc, 2, 4);
    acc += __shfl_xor(acc, 1, 4);
    if (q == 0) ypred[(b * 63 + t) * 16 + o] = acc;
}

// ---------------------------------------------------------------------------
extern "C" void kernel_launch(void* const* d_in, const int* in_sizes, int n_in,
                              void* d_out, int out_size, void* d_ws, size_t ws_size,
                              hipStream_t stream) {
    const float* xs      = (const float*)d_in[0];
    const float* us      = (const float*)d_in[1];
    const float* x_gamma = (const float*)d_in[2];
    const float* x_beta  = (const float*)d_in[3];
    const float* xW1     = (const float*)d_in[4];
    const float* xb1     = (const float*)d_in[5];
    const float* xW2     = (const float*)d_in[6];
    const float* xb2     = (const float*)d_in[7];
    const float* xW3     = (const float*)d_in[8];
    const float* x_scale = (const float*)d_in[9];
    const float* u_gamma = (const float*)d_in[10];
    const float* u_beta  = (const float*)d_in[11];
    const float* uW1     = (const float*)d_in[12];
    const float* ub1     = (const float*)d_in[13];
    const float* uW2     = (const float*)d_in[14];
    const float* ub2     = (const float*)d_in[15];
    const float* uW3     = (const float*)d_in[16];
    const float* u_scale = (const float*)d_in[17];
    const float* reL     = (const float*)d_in[18];
    const float* imL     = (const float*)d_in[19];
    const float* C_W     = (const float*)d_in[20];

    char* ws = (char*)d_ws;
    size_t off = 0;
    auto alloc = [&](size_t bytes) -> char* {
        char* p = ws + off;
        off += (bytes + 255) & ~(size_t)255;
        return p;
    };
    float*  part = (float*)alloc(96 * 32 * 4);
    bf16_t* xW1t = (bf16_t*)alloc((size_t)64 * 256 * 32 * 2);
    float*  xb1p = (float*) alloc((size_t)64 * 256 * 4);
    bf16_t* xW2t = (bf16_t*)alloc((size_t)64 * 256 * 256 * 2);
    bf16_t* xW3t = (bf16_t*)alloc((size_t)64 * 128 * 256 * 2);
    bf16_t* uW1t = (bf16_t*)alloc((size_t)64 * 256 * 32 * 2);
    float*  ub1p = (float*) alloc((size_t)64 * 256 * 4);
    bf16_t* uW2t = (bf16_t*)alloc((size_t)64 * 256 * 256 * 2);
    bf16_t* uW3t = (bf16_t*)alloc((size_t)64 * 128 * 256 * 2);
    float*  psi0 = (float*) alloc((size_t)64 * 128 * 4);
    bf16_t* phi  = (bf16_t*)alloc((size_t)64 * 4096 * 128 * 2);   // [j][m][128]
    bf16_t* psiu = (bf16_t*)alloc((size_t)64 * 4032 * 128 * 2);   // [j][m][128]
    float*  scr  = (float*) alloc((size_t)512 * 63 * 128 * 4);    // scan partials

    float* y_out     = (float*)d_out;
    float* ypred_out = y_out + 64 * 63 * 16;

    prep_all_kernel<<<12576, 256, 0, stream>>>(
        xW1, xb1, x_gamma, x_beta, uW1, ub1, u_gamma, u_beta,
        xW2, uW2, xW3, uW3, x_scale, u_scale, ub2, xs, us,
        xW1t, xb1p, uW1t, ub1p, xW2t, uW2t, xW3t, uW3t, psi0, part);
    fused_mlp_kernel<<<4096, 512, 0, stream>>>(
        xs, us, part,
        xW1t, xb1p, xW2t, xb2, xW3t, uW1t, ub1p, uW2t, ub2, uW3t, phi, psiu);
    y_kernel<<<256, 256, 0, stream>>>(phi, C_W, y_out);
    scan_kernel<<<512, 256, 0, stream>>>(phi, psiu, psi0, reL, imL, scr);
    decode_kernel<<<dim3(63, 64), 64, 0, stream>>>(scr, C_W, ypred_out);
}